// Round 11
// baseline (2723.797 us; speedup 1.0000x reference)
//
#include <hip/hip_runtime.h>

#define SEQ 999
#define DTC 0.01f
#define NXW 125
#define NW1 64
#define IDX_C0  0
#define IDX_C1  32
#define IDX_CW1 64
#define IDX_FLG 96
#define SYNC_DWORDS 4096

typedef _Float16 h2 __attribute__((ext_vector_type(2)));
typedef unsigned u32x4 __attribute__((ext_vector_type(4)));
typedef float f32x4 __attribute__((ext_vector_type(4)));

__device__ __forceinline__ h2 u2h(unsigned u){ return __builtin_bit_cast(h2,u); }
__device__ __forceinline__ h2 pkfma(h2 a, h2 b, h2 c){ return __builtin_elementwise_fma(a,b,c); }

__device__ __forceinline__ float softplusf(float x){
  return fmaxf(x,0.f) + log1pf(__expf(-fabsf(x)));
}
__device__ __forceinline__ float sigmoidf(float x){ return 1.f/(1.f+__expf(-x)); }
__device__ __forceinline__ float tanh_fast(float x){
  float e = __expf(-2.f*x); return (1.f-e)/(1.f+e);
}

template<int SLP>
__device__ __forceinline__ void waitge(unsigned* p, unsigned v){
  if (__hip_atomic_load(p,__ATOMIC_RELAXED,__HIP_MEMORY_SCOPE_AGENT) < v){
    do { __builtin_amdgcn_s_sleep(SLP); }
    while (__hip_atomic_load(p,__ATOMIC_RELAXED,__HIP_MEMORY_SCOPE_AGENT) < v);
  }
  (void)__hip_atomic_load(p,__ATOMIC_ACQUIRE,__HIP_MEMORY_SCOPE_AGENT);
}

__global__ void k_init(unsigned* sync){
  for (int i=threadIdx.x; i<SYNC_DWORDS; i+=512) sync[i] = 0u;
}

// Whh -> MFMA A-frag layout: frag f=(tile*8+q), lane l, h2-pair jp holds
// W[tile*16+(l&15)][q*32+(l>>4)*8+2jp .. +1].  (k-order matches B-frag k-order:
// any HW k-permutation applied to BOTH A and B cancels in the dot.)
// wih1 -> TRANSPOSED (for do_xw, unchanged).
__global__ void k_convert(const float* __restrict__ whh0, const float* __restrict__ wih1,
                          const float* __restrict__ whh1,
                          const float* __restrict__ bih0, const float* __restrict__ bhh0,
                          const float* __restrict__ bih1, const float* __restrict__ bhh1,
                          h2* __restrict__ aW0, h2* __restrict__ wih1T, h2* __restrict__ aW1,
                          float* __restrict__ bs0, float* __restrict__ bs1){
  int o = blockIdx.x*256 + threadIdx.x;
  if (o < 131072){
    int f = o >> 8, rem = o & 255, l = rem >> 2, jp = rem & 3;
    int tile = f >> 3, q = f & 7;
    int row = tile*16 + (l & 15);
    int col = q*32 + ((l >> 4) << 3) + (jp << 1);
    const float* s = whh0 + row*256 + col;
    aW0[o] = h2{(_Float16)s[0], (_Float16)s[1]};
  } else if (o < 262144){
    int oo = o - 131072; int r = oo & 1023, c2 = oo >> 10;
    const float* s = wih1 + r*256 + 2*c2;
    wih1T[oo] = h2{(_Float16)s[0], (_Float16)s[1]};
  } else if (o < 393216){
    int oo = o - 262144;
    int f = oo >> 8, rem = oo & 255, l = rem >> 2, jp = rem & 3;
    int tile = f >> 3, q = f & 7;
    int row = tile*16 + (l & 15);
    int col = q*32 + ((l >> 4) << 3) + (jp << 1);
    const float* s = whh1 + row*256 + col;
    aW1[oo] = h2{(_Float16)s[0], (_Float16)s[1]};
  } else if (o < 394240){
    int r = o - 393216; bs0[r] = bih0[r] + bhh0[r];
  } else if (o < 395264){
    int r = o - 394240; bs1[r] = bih1[r] + bhh1[r];
  }
}

// ---- MFMA asm helpers (A from AGPR "a" / tied VGPR / LDS-loaded VGPR) ----
#define MM_A(ACC,TT,Q) asm volatile("v_mfma_f32_16x16x32_f16 %0, %1, %2, %0" \
  : "+v"(ACC) : "a"(agA[TT][Q]), "v"(Bf[Q]))
#define MM_V(ACC,TT,Q) asm volatile("v_mfma_f32_16x16x32_f16 %0, %1, %2, %0" \
  : "+v"(ACC), "+v"(avA[TT][Q]) : "v"(Bf[Q]))
#define MM_L(ACC,SL,Q) asm volatile("v_mfma_f32_16x16x32_f16 %0, %1, %2, %0" \
  : "+v"(ACC) : "v"(aspill[wv][(SL)*8+(Q)][lane]), "v"(Bf[Q]))
#define MI_A(ACC,TT)   asm volatile("v_mfma_f32_16x16x32_f16 %0, %1, %2, %3" \
  : "=&v"(ACC) : "a"(agA[TT][0]), "v"(Bf[0]), "v"(zero4))
#define MI_V(ACC,TT)   asm volatile("v_mfma_f32_16x16x32_f16 %0, %1, %2, %3" \
  : "=&v"(ACC), "+v"(avA[TT][0]) : "v"(Bf[0]), "v"(zero4))
#define MI_L(ACC,SL)   asm volatile("v_mfma_f32_16x16x32_f16 %0, %1, %2, %3" \
  : "=&v"(ACC) : "v"(aspill[wv][(SL)*8][lane]), "v"(Bf[0]), "v"(zero4))

#define PAIRSEQ(I0,I1,M0,M1,P0,P1,A0,A1) \
  I0(A0,P0);      I1(A1,P1); \
  M0(A0,P0,1);    M1(A1,P1,1); \
  M0(A0,P0,2);    M1(A1,P1,2); \
  M0(A0,P0,3);    M1(A1,P1,3); \
  M0(A0,P0,4);    M1(A1,P1,4); \
  M0(A0,P0,5);    M1(A1,P1,5); \
  M0(A0,P0,6);    M1(A1,P1,6); \
  M0(A0,P0,7);    M1(A1,P1,7);

#define GW(ACC, OFF) asm volatile("ds_write_b128 %0, %1 offset:" #OFF \
  : : "v"(gaddr), "v"(ACC) : "memory")
#define WPAIR(AA,AB,O0,O1) do{ if (l15){ GW(AA,O0); GW(AB,O1); } }while(0)

// ===== LSTM layer on ONE CU via MFMA. 256 thr (1 wave/SIMD, 512-reg budget).
// Wave wv owns row-tiles wv*16..+15. Per wave 128 A-frags: tiles0-6 AGPR,
// 7-11 arch VGPR, 12-15 LDS. B = h replicated over cols. D: col=lane&15 (dup),
// row=(lane>>4)*4+reg (verified layout) -> lanes with (lane&15)==0 write gates.
template<int MODE>
__device__ void do_layer(const u32x4* __restrict__ wA, const float* __restrict__ wih0,
                         const float* __restrict__ bs, const float* __restrict__ X,
                         const float* __restrict__ xw1,
                         _Float16* __restrict__ h0h, float* __restrict__ h1f,
                         unsigned* prog, unsigned* sync,
                         u32x4 (*aspill)[32][64], float* gatesL,
                         _Float16* hbuf, float* xlds)
{
  const int tid  = threadIdx.x;
  const int lane = tid & 63;
  const int wv   = tid >> 6;
  const bool l15 = (lane & 15) == 0;

  u32x4 agA[7][8];
  u32x4 avA[5][8];
#pragma unroll
  for (int tt=0;tt<7;++tt)
#pragma unroll
    for (int q=0;q<8;++q)
      agA[tt][q] = wA[(size_t)(((wv*16+tt)*8+q)*64) + lane];
#pragma unroll
  for (int tt=0;tt<7;++tt)
#pragma unroll
    for (int q=0;q<8;++q) asm("" : "+a"(agA[tt][q]));
#pragma unroll
  for (int tt=0;tt<5;++tt)
#pragma unroll
    for (int q=0;q<8;++q){
      avA[tt][q] = wA[(size_t)(((wv*16+7+tt)*8+q)*64) + lane];
      asm("" : "+v"(avA[tt][q]));
    }
#pragma unroll
  for (int tt=0;tt<4;++tt)
#pragma unroll
    for (int q=0;q<8;++q)
      aspill[wv][tt*8+q][lane] = wA[(size_t)(((wv*16+12+tt)*8+q)*64) + lane];

  f32x4 zero4 = {0.f,0.f,0.f,0.f};
  asm("" : "+v"(zero4));

  float wxa[4], wxb[4], bv[4];
  if (MODE == 0){
#pragma unroll
    for (int g=0;g<4;++g){
      wxa[g] = wih0[(g*256+tid)*2];
      wxb[g] = wih0[(g*256+tid)*2+1];
      bv[g]  = bs[g*256+tid];
    }
    for (int i=tid;i<2*SEQ;i+=256) xlds[i]=X[i];
  }
  hbuf[tid] = (_Float16)0.f;
  __syncthreads();

  float4 nx = {0,0,0,0}, nx2 = {0,0,0,0};
  if (MODE == 1){
    if (tid==0) waitge<2>(&sync[IDX_FLG+0], 1u);
    __syncthreads();
    nx = *(const float4*)&xw1[(size_t)(tid<<2)];
  }

  const unsigned gbase = (unsigned)(unsigned long long)(void*)gatesL;
  const unsigned gaddr = gbase + ((unsigned)(wv*256 + ((lane>>4)<<2)) << 2);
  const char* hbp = (const char*)hbuf + ((lane>>4)<<4);
  float c = 0.f;

#pragma unroll 1
  for (int t=0;t<SEQ;++t){
    if (MODE==1 && t+1<SEQ){
      if (((t+1)&7)==0){
        if (tid==0) waitge<2>(&sync[IDX_FLG + ((t+1)>>3)*32], 1u);
        __syncthreads();
      }
      nx2 = *(const float4*)&xw1[(size_t)(t+1)*1024 + (tid<<2)];
    }

    // ---- B-frags: h replicated across cols; 8 reads of 16B ----
    u32x4 Bf[8];
#pragma unroll
    for (int q=0;q<8;++q) Bf[q] = *(const u32x4*)(hbp + q*64);

    f32x4 ac0, ac1, ac2, ac3;
    PAIRSEQ(MI_A, MI_A, MM_A, MM_A, 0, 1, ac0, ac1);         // tiles 0,1
    PAIRSEQ(MI_A, MI_A, MM_A, MM_A, 2, 3, ac2, ac3);         // tiles 2,3
    WPAIR(ac0, ac1, 0, 64);
    PAIRSEQ(MI_A, MI_A, MM_A, MM_A, 4, 5, ac0, ac1);         // tiles 4,5
    WPAIR(ac2, ac3, 128, 192);
    PAIRSEQ(MI_A, MI_V, MM_A, MM_V, 6, 0, ac2, ac3);         // tiles 6,7
    WPAIR(ac0, ac1, 256, 320);
    PAIRSEQ(MI_V, MI_V, MM_V, MM_V, 1, 2, ac0, ac1);         // tiles 8,9
    WPAIR(ac2, ac3, 384, 448);
    PAIRSEQ(MI_V, MI_V, MM_V, MM_V, 3, 4, ac2, ac3);         // tiles 10,11
    WPAIR(ac0, ac1, 512, 576);
    PAIRSEQ(MI_L, MI_L, MM_L, MM_L, 0, 1, ac0, ac1);         // tiles 12,13
    WPAIR(ac2, ac3, 640, 704);
    PAIRSEQ(MI_L, MI_L, MM_L, MM_L, 2, 3, ac2, ac3);         // tiles 14,15
    WPAIR(ac0, ac1, 768, 832);
    asm volatile("s_nop 7\n\ts_nop 7");
    WPAIR(ac2, ac3, 896, 960);

    __syncthreads();                                   // B1: gates complete

    // ---- update phase: thread k = tid owns unit k ----
    {
      const int k = tid;
      float gi = gatesL[k], gf = gatesL[256+k], gg = gatesL[512+k], go = gatesL[768+k];
      if (MODE==0){
        float2 xv = *(const float2*)&xlds[2*t];
        gi += fmaf(wxb[0], xv.y, fmaf(wxa[0], xv.x, bv[0]));
        gf += fmaf(wxb[1], xv.y, fmaf(wxa[1], xv.x, bv[1]));
        gg += fmaf(wxb[2], xv.y, fmaf(wxa[2], xv.x, bv[2]));
        go += fmaf(wxb[3], xv.y, fmaf(wxa[3], xv.x, bv[3]));
      } else {
        gi += nx.x; gf += nx.y; gg += nx.z; go += nx.w;
        nx = nx2;
      }
      float i_ = sigmoidf(gi), f_ = sigmoidf(gf);
      float g_ = tanh_fast(gg), o_ = sigmoidf(go);
      c = fmaf(f_, c, i_*g_);
      float h = o_ * tanh_fast(c);
      hbuf[k] = (_Float16)h;
      if (MODE==0) h0h[t*256+k] = (_Float16)h;
      else         h1f[t*256+k] = h;
    }
    __syncthreads();                                   // B2: h visible, stores drained
    if (tid==0 && ((t&7)==7 || t==SEQ-1))
      __hip_atomic_store(prog,(unsigned)(t+1),__ATOMIC_RELEASE,__HIP_MEMORY_SCOPE_AGENT);
  }
}

// xw chunk worker: 256 threads, thread owns unit tid's 4 gate rows; out [t][unit][gate]
__device__ void do_xw(int b, const h2* __restrict__ wih1T, const float* __restrict__ bs1,
                      const _Float16* __restrict__ h0h, float* __restrict__ xw1,
                      unsigned* sync)
{
  const int tid = threadIdx.x;
  const int t0 = 8*b;
  const int tend = (t0+8 < SEQ) ? t0+8 : SEQ;
  if (tid==0) waitge<32>(&sync[IDX_C0], (unsigned)tend);
  __syncthreads();
  const float b0=bs1[tid], b1=bs1[256+tid], b2=bs1[512+tid], b3=bs1[768+tid];
#pragma unroll 1
  for (int t=t0;t<tend;++t){
    const uint4* hv4 = (const uint4*)(h0h + (size_t)t*256);
    float f0=b0, f1=b1, f2=b2, f3=b3;
    h2 p0={0,0}, p1={0,0}, p2={0,0}, p3={0,0};
#pragma unroll
    for (int q=0;q<32;++q){
      uint4 hv = hv4[q];
      h2 hx=u2h(hv.x), hy=u2h(hv.y), hz=u2h(hv.z), hw=u2h(hv.w);
      const int cb = 4*q*1024;
      p0 = pkfma(hx, wih1T[cb + tid      ], p0);
      p1 = pkfma(hx, wih1T[cb + 256+tid  ], p1);
      p2 = pkfma(hx, wih1T[cb + 512+tid  ], p2);
      p3 = pkfma(hx, wih1T[cb + 768+tid  ], p3);
      p0 = pkfma(hy, wih1T[cb+1024 + tid    ], p0);
      p1 = pkfma(hy, wih1T[cb+1024 + 256+tid], p1);
      p2 = pkfma(hy, wih1T[cb+1024 + 512+tid], p2);
      p3 = pkfma(hy, wih1T[cb+1024 + 768+tid], p3);
      p0 = pkfma(hz, wih1T[cb+2048 + tid    ], p0);
      p1 = pkfma(hz, wih1T[cb+2048 + 256+tid], p1);
      p2 = pkfma(hz, wih1T[cb+2048 + 512+tid], p2);
      p3 = pkfma(hz, wih1T[cb+2048 + 768+tid], p3);
      p0 = pkfma(hw, wih1T[cb+3072 + tid    ], p0);
      p1 = pkfma(hw, wih1T[cb+3072 + 256+tid], p1);
      p2 = pkfma(hw, wih1T[cb+3072 + 512+tid], p2);
      p3 = pkfma(hw, wih1T[cb+3072 + 768+tid], p3);
      if ((q&1)==1){
        f0 += (float)p0.x + (float)p0.y; p0={0,0};
        f1 += (float)p1.x + (float)p1.y; p1={0,0};
        f2 += (float)p2.x + (float)p2.y; p2={0,0};
        f3 += (float)p3.x + (float)p3.y; p3={0,0};
      }
    }
    *(float4*)&xw1[(size_t)t*1024 + (tid<<2)] = float4{f0,f1,f2,f3};
  }
  __syncthreads();
  if (tid==0)
    __hip_atomic_store(&sync[IDX_FLG + 32*b], 1u, __ATOMIC_RELEASE, __HIP_MEMORY_SCOPE_AGENT);
}

// W1 streamer: 256 threads, 4 rows/block, chunk-gated on L1 progress
__device__ void do_w1(int w, const float* __restrict__ W1, const float* __restrict__ b1,
                      const float* __restrict__ h1f, float* __restrict__ z1,
                      unsigned* sync, float* red)
{
  const int tid = threadIdx.x;
#pragma unroll 1
  for (int rr=0;rr<4;++rr){
    const int j = w*4 + rr;
    const float* wrow = W1 + (size_t)j*(SEQ*256);
    float acc = 0.f;
#pragma unroll 1
    for (int kc=0;kc<8;++kc){
      const int lo = kc*128, hi = (kc==7) ? SEQ : lo+128;
      if (tid==0) waitge<64>(&sync[IDX_C1], (unsigned)hi);
      __syncthreads();
      const float4* w4 = (const float4*)(wrow + lo*256);
      const float4* h4 = (const float4*)(h1f + lo*256);
      const int n4 = (hi-lo)*64;
      for (int q=tid; q<n4; q+=256){
        float4 a=w4[q], b=h4[q];
        acc=fmaf(a.x,b.x,acc); acc=fmaf(a.y,b.y,acc);
        acc=fmaf(a.z,b.z,acc); acc=fmaf(a.w,b.w,acc);
      }
      __syncthreads();
    }
    red[tid]=acc; __syncthreads();
    for (int s=128;s>0;s>>=1){ if(tid<s) red[tid]+=red[tid+s]; __syncthreads(); }
    if (tid==0) z1[j] = softplusf(red[0] + b1[j]);
    __syncthreads();
  }
  if (tid==0)
    __hip_atomic_fetch_add(&sync[IDX_CW1], 1u, __ATOMIC_RELEASE, __HIP_MEMORY_SCOPE_AGENT);
}

__device__ void do_head(const float* __restrict__ W2, const float* __restrict__ b2,
                        const float* __restrict__ W3, const float* __restrict__ b3,
                        const float* __restrict__ z1, const float* __restrict__ data,
                        float* __restrict__ out, unsigned* sync, float* red)
{
  const int tid = threadIdx.x;
  if (tid==0) waitge<64>(&sync[IDX_CW1], (unsigned)NW1);
  __syncthreads();
  red[tid] = z1[tid];
  __syncthreads();
  if (tid<128){
    float acc = b2[tid];
#pragma unroll 4
    for (int kk=0;kk<256;++kk) acc = fmaf(W2[tid*256+kk], red[kk], acc);
    red[256+tid] = softplusf(acc);
  }
  __syncthreads();
  if (tid<4){
    float a = b3[tid];
#pragma unroll 4
    for (int kk=0;kk<128;++kk) a = fmaf(W3[tid*128+kk], red[256+kk], a);
    red[384+tid] = a;
  }
  __syncthreads();
  if (tid==0){
    float a=red[384], b=red[385], cc=red[386], d=red[387];
    float R=data[0], J=data[1];
#pragma unroll 1
    for (int t=0;t<SEQ;++t){
      float RJ=R*J;
      float Rn = R + DTC*(a*R - b*RJ);
      float Jn = J + DTC*(d*RJ - cc*J);
      out[2*t]=Rn; out[2*t+1]=Jn;
      R=Rn; J=Jn;
    }
  }
}

// roles: 0=L0 | 1=L1 | 2..126 xw | 127..190 W1 | 191 head. 256 thr, ~142KB LDS -> 1/CU.
__global__ __launch_bounds__(256,1)
void k_fused(const u32x4* __restrict__ aW0, const h2* __restrict__ wih1T,
             const u32x4* __restrict__ aW1, const float* __restrict__ bs0,
             const float* __restrict__ bs1, const float* __restrict__ Wih0,
             const float* __restrict__ X, _Float16* h0h, float* xw1, float* h1f,
             float* z1, const float* __restrict__ W1, const float* __restrict__ b1,
             const float* __restrict__ W2, const float* __restrict__ b2,
             const float* __restrict__ W3, const float* __restrict__ b3,
             const float* __restrict__ data, float* out, unsigned* sync)
{
  __shared__ __align__(16) u32x4 aspill[4][32][64];     // 128 KB (LDS A-frags)
  __shared__ __align__(16) float gatesL[1024];          // 4 KB
  __shared__ __align__(16) _Float16 hbuf[256];          // 512 B
  __shared__ float xlds[2*SEQ];                         // 8 KB
  __shared__ float red[512];                            // 2 KB

  const int role = blockIdx.x;
  if (role == 0)
    do_layer<0>(aW0, Wih0, bs0, X, nullptr, h0h, nullptr,
                &sync[IDX_C0], sync, aspill, gatesL, hbuf, xlds);
  else if (role == 1)
    do_layer<1>(aW1, nullptr, nullptr, nullptr, xw1, nullptr, h1f,
                &sync[IDX_C1], sync, aspill, gatesL, hbuf, xlds);
  else if (role < 2+NXW)
    do_xw(role-2, wih1T, bs1, h0h, xw1, sync);
  else if (role < 2+NXW+NW1)
    do_w1(role-(2+NXW), W1, b1, h1f, z1, sync, red);
  else
    do_head(W2, b2, W3, b3, z1, data, out, sync, red);
}

extern "C" void kernel_launch(void* const* d_in, const int* in_sizes, int n_in,
                              void* d_out, int out_size, void* d_ws, size_t ws_size,
                              hipStream_t stream){
  const float* X    = (const float*)d_in[0];
  const float* data = (const float*)d_in[1];
  const float* Wih0 = (const float*)d_in[2];
  const float* Whh0 = (const float*)d_in[3];
  const float* bih0 = (const float*)d_in[4];
  const float* bhh0 = (const float*)d_in[5];
  const float* Wih1 = (const float*)d_in[6];
  const float* Whh1 = (const float*)d_in[7];
  const float* bih1 = (const float*)d_in[8];
  const float* bhh1 = (const float*)d_in[9];
  const float* W1   = (const float*)d_in[10];
  const float* b1   = (const float*)d_in[11];
  const float* W2   = (const float*)d_in[12];
  const float* b2   = (const float*)d_in[13];
  const float* W3   = (const float*)d_in[14];
  const float* b3   = (const float*)d_in[15];
  float* out = (float*)d_out;

  char* w = (char*)d_ws;
  h2*       aW0c  = (h2*)(w + 0);              // 512 KB A-frag f16 (layer0)
  h2*       wih1T = (h2*)(w + 524288);         // 512 KB transposed f16
  h2*       aW1c  = (h2*)(w + 1048576);        // 512 KB A-frag f16 (layer1)
  float*    bs0   = (float*)(w + 1572864);     // 4 KB
  float*    bs1   = (float*)(w + 1576960);     // 4 KB
  _Float16* h0h   = (_Float16*)(w + 1581056);  // 511,488 B
  float*    xw1   = (float*)(w + 2097152);     // 4,091,904 B  [t][unit][gate]
  float*    h1f   = (float*)(w + 6189056);     // 1,022,976 B
  float*    z1    = (float*)(w + 7212032);     // 1 KB
  unsigned* sync  = (unsigned*)(w + 7213056);  // 16 KB padded counters/flags

  k_init<<<1, 512, 0, stream>>>(sync);
  k_convert<<<1544, 256, 0, stream>>>(Whh0, Wih1, Whh1, bih0, bhh0, bih1, bhh1,
                                      aW0c, wih1T, aW1c, bs0, bs1);
  k_fused<<<2+NXW+NW1+1, 256, 0, stream>>>((const u32x4*)aW0c, wih1T, (const u32x4*)aW1c,
                                           bs0, bs1, Wih0, X, h0h, xw1, h1f, z1,
                                           W1, b1, W2, b2, W3, b3, data, out, sync);
}